// Round 3
// baseline (321.631 us; speedup 1.0000x reference)
//
#include <hip/hip_runtime.h>

// NCC weight loss — fused, z-streaming, software-pipelined single-barrier loop.
// Pipeline at iteration t: A(plane c0-2+t) -> zsL[t&1]
//                          B(reads zsL[(t-1)&1]) -> sx[t&1]
//                          C(reads sx[(t-1)&1])  -> output z = c0-6+t
// Dims fixed: (N=2, C=1, D=160, H=192, W=224), win=5, fp32.
#define N_  2
#define D_  160
#define H_  192
#define W_  224
#define TW  32            // output tile width  (x)
#define TH  8             // output tile height (y)
#define ZCH 20            // z-chunk per block
#define NZC (D_/ZCH)      // 8
#define NST (ZCH+6)       // 26 pipelined steps
#define HWH (TW+4)        // 36 halo width (also sx row pad: 36 ≡ 4 mod 32)
#define HHH (TH+4)        // 12 halo height
#define HW_ (H_*W_)
#define TOT (N_*D_*H_*W_) // 13,762,560

__global__ __launch_bounds__(256, 4) void ncc_kernel(
    const float* __restrict__ I, const float* __restrict__ J,
    const float* __restrict__ Wm, float* __restrict__ out)
{
    __shared__ __align__(16) float zsL[2][5][HHH][HWH]; // z-summed quantity planes
    __shared__ __align__(16) float sx [2][5][HHH][HWH]; // x-box-summed (cols 0..31)
    __shared__ float red[4];

    const int tid = threadIdx.x;
    const int bx = blockIdx.x, by = blockIdx.y;
    const int n  = blockIdx.z / NZC;
    const int c0 = (blockIdx.z % NZC) * ZCH;
    const int wbase = bx * TW - 2;
    const int hbase = by * TH - 2;
    const int nb = n * (D_ * HW_);

    // ---- Phase A ownership: 216 threads own 2 adjacent halo columns ----
    const bool aAct = tid < 216;
    const int arow = tid / 18;           // 0..11
    const int ag   = tid % 18;           // 0..17
    const int ah   = hbase + arow;
    const int aw0  = wbase + 2 * ag;     // even; aw0<W_ implies aw0+1<W_ (W even)
    const bool aok = aAct && ((unsigned)ah < (unsigned)H_) && ((unsigned)aw0 < (unsigned)W_);
    const int aoff = ah * W_ + aw0;

    // per-column z-ring of raw I,J + incremental z-sums of the 5 quantities
    float rI0[5], rJ0[5], rI1[5], rJ1[5];
    float zs0[5], zs1[5];
#pragma unroll
    for (int k = 0; k < 5; ++k) { rI0[k]=0.f; rJ0[k]=0.f; rI1[k]=0.f; rJ1[k]=0.f; }
#pragma unroll
    for (int a = 0; a < 5; ++a) { zs0[a]=0.f; zs1[a]=0.f; }

    // ---- Phase B ownership: 96 threads, 4 x-outputs each ----
    const int brow = tid >> 3;           // 0..11 (for tid<96)
    const int bx0  = (tid & 7) * 4;

    // ---- Phase C ownership: 64 threads, 4 outputs each ----
    const int cty = tid >> 3;            // 0..7 (for tid<64)
    const int cx0 = (tid & 7) * 4;
    const int ch  = by * TH + cty;
    const int cw  = bx * TW + cx0;

    // prefetch registers for Phase A (plane c0-2 first)
    float2 pI = make_float2(0.f, 0.f), pJ = make_float2(0.f, 0.f);
    {
        const int z0 = c0 - 2;
        if (aok && z0 >= 0) {
            const int g = nb + z0 * HW_ + aoff;
            pI = *(const float2*)&I[g];
            pJ = *(const float2*)&J[g];
        }
    }

    float acc = 0.f;
    const float inv125 = 1.0f / 125.0f;

    for (int t = 0; t < NST; ++t) {
        const int cur = t & 1, prv = cur ^ 1;

        // ---------- Phase A: consume prefetched plane, issue next, stage z-sums
        if (t <= ZCH + 3 && aAct) {
            const float iv0 = pI.x, iv1 = pI.y, jv0 = pJ.x, jv1 = pJ.y;

            // issue prefetch for plane c0-1+t (consumed next iteration)
            float2 nI = make_float2(0.f, 0.f), nJ = make_float2(0.f, 0.f);
            const int zn = c0 - 1 + t;
            if (t < ZCH + 3 && aok && (unsigned)zn < (unsigned)D_) {
                const int g = nb + zn * HW_ + aoff;
                nI = *(const float2*)&I[g];
                nJ = *(const float2*)&J[g];
            }
            pI = nI; pJ = nJ;

            {   // column 0: incremental z-window update
                const float oi = rI0[0], oj = rJ0[0];
                zs0[0] += iv0 - oi;
                zs0[1] += jv0 - oj;
                zs0[2] += iv0*iv0 - oi*oi;
                zs0[3] += jv0*jv0 - oj*oj;
                zs0[4] += iv0*jv0 - oi*oj;
#pragma unroll
                for (int k = 0; k < 4; ++k) { rI0[k]=rI0[k+1]; rJ0[k]=rJ0[k+1]; }
                rI0[4] = iv0; rJ0[4] = jv0;
            }
            {   // column 1
                const float oi = rI1[0], oj = rJ1[0];
                zs1[0] += iv1 - oi;
                zs1[1] += jv1 - oj;
                zs1[2] += iv1*iv1 - oi*oi;
                zs1[3] += jv1*jv1 - oj*oj;
                zs1[4] += iv1*jv1 - oi*oj;
#pragma unroll
                for (int k = 0; k < 4; ++k) { rI1[k]=rI1[k+1]; rJ1[k]=rJ1[k+1]; }
                rI1[4] = iv1; rJ1[4] = jv1;
            }
#pragma unroll
            for (int a = 0; a < 5; ++a)
                *(float2*)&zsL[cur][a][arow][2*ag] = make_float2(zs0[a], zs1[a]);
        }

        // ---------- Phase B: x box-sum (36 -> 32) on previous iteration's zsL
        if (t >= 1 && t <= ZCH + 4 && tid < 96) {
#pragma unroll
            for (int a = 0; a < 5; ++a) {
                const float4 v0 = *(const float4*)&zsL[prv][a][brow][bx0];
                const float4 v1 = *(const float4*)&zsL[prv][a][brow][bx0 + 4];
                const float m  = v0.y + v0.z + v0.w;
                const float u1 = v1.x + v1.y;
                const float u2 = u1 + v1.z;
                const float o0 = v0.x + m + v1.x;
                const float o1 = m + u1;
                const float o2 = (v0.z + v0.w) + u2;
                const float o3 = v0.w + (u2 + v1.w);
                *(float4*)&sx[cur][a][brow][bx0] = make_float4(o0, o1, o2, o3);
            }
        }

        // ---------- Phase C: y box-sum + cc on sx written two planes ago
        if (t >= 6 && tid < 64) {
            const int zo = c0 - 6 + t;       // in [c0, c0+ZCH-1]
            float4 S[5];
#pragma unroll
            for (int a = 0; a < 5; ++a) {
                float4 v = *(const float4*)&sx[prv][a][cty][cx0];
#pragma unroll
                for (int k = 1; k < 5; ++k) {
                    const float4 w = *(const float4*)&sx[prv][a][cty + k][cx0];
                    v.x += w.x; v.y += w.y; v.z += w.z; v.w += w.w;
                }
                S[a] = v;
            }
            const float4 wm = *(const float4*)&Wm[(nb + zo * HW_) + ch * W_ + cw];
            {
                const float cr = S[4].x - S[0].x * S[1].x * inv125;
                const float vi = S[2].x - S[0].x * S[0].x * inv125;
                const float vj = S[3].x - S[1].x * S[1].x * inv125;
                acc += wm.x * (cr * cr) * __builtin_amdgcn_rcpf(vi * vj + 1e-8f);
            }
            {
                const float cr = S[4].y - S[0].y * S[1].y * inv125;
                const float vi = S[2].y - S[0].y * S[0].y * inv125;
                const float vj = S[3].y - S[1].y * S[1].y * inv125;
                acc += wm.y * (cr * cr) * __builtin_amdgcn_rcpf(vi * vj + 1e-8f);
            }
            {
                const float cr = S[4].z - S[0].z * S[1].z * inv125;
                const float vi = S[2].z - S[0].z * S[0].z * inv125;
                const float vj = S[3].z - S[1].z * S[1].z * inv125;
                acc += wm.z * (cr * cr) * __builtin_amdgcn_rcpf(vi * vj + 1e-8f);
            }
            {
                const float cr = S[4].w - S[0].w * S[1].w * inv125;
                const float vi = S[2].w - S[0].w * S[0].w * inv125;
                const float vj = S[3].w - S[1].w * S[1].w * inv125;
                acc += wm.w * (cr * cr) * __builtin_amdgcn_rcpf(vi * vj + 1e-8f);
            }
        }

        // single barrier: protects zsL[cur]/sx[cur] RAW for t+1 and the
        // WAR on zsL[prv]/sx[prv] which t+1's A/B will overwrite.
        __syncthreads();
    }

    // Block reduction: wave64 shuffle, then cross-wave via LDS
#pragma unroll
    for (int off = 32; off > 0; off >>= 1)
        acc += __shfl_down(acc, off, 64);
    const int wave = tid >> 6;
    const int lane = tid & 63;
    if (lane == 0) red[wave] = acc;
    __syncthreads();
    if (tid == 0) {
        const float t = red[0] + red[1] + red[2] + red[3];
        atomicAdd(out, t * (-1.0f / (float)TOT));
    }
}

extern "C" void kernel_launch(void* const* d_in, const int* in_sizes, int n_in,
                              void* d_out, int out_size, void* d_ws, size_t ws_size,
                              hipStream_t stream)
{
    const float* I  = (const float*)d_in[0];
    const float* J  = (const float*)d_in[1];
    const float* Wm = (const float*)d_in[2];
    float* out = (float*)d_out;

    hipMemsetAsync(out, 0, sizeof(float), stream);

    dim3 grid(W_ / TW, H_ / TH, N_ * NZC);  // (7, 24, 16) = 2688 blocks
    dim3 block(256);
    hipLaunchKernelGGL(ncc_kernel, grid, block, 0, stream, I, J, Wm, out);
}

// Round 4
// 258.689 us; speedup vs baseline: 1.2433x; 1.2433x over previous
//
#include <hip/hip_runtime.h>

// NCC weight loss — fused z-streaming kernel. Single-buffer LDS (r2 structure),
// global loads software-pipelined one step ahead (registers only, no LDS dbuf).
// Step order: B(t-1) | barrier | A(t) + C(t-1) | barrier.
// Dims fixed: (N=2, C=1, D=160, H=192, W=224), win=5, fp32.
#define N_  2
#define D_  160
#define H_  192
#define W_  224
#define TW  32            // output tile width  (x)
#define TH  8             // output tile height (y)
#define ZCH 32            // z-chunk per block
#define NZC (D_/ZCH)      // 5
#define HWH (TW+4)        // 36 halo width
#define HHH (TH+4)        // 12 halo height
#define HW_ (H_*W_)
#define TOT (N_*D_*H_*W_) // 13,762,560

__global__ __launch_bounds__(256) void ncc_kernel(
    const float* __restrict__ I, const float* __restrict__ J,
    const float* __restrict__ Wm, float* __restrict__ out)
{
    __shared__ __align__(16) float zsL[5][HHH][HWH]; // z-summed quantity planes
    __shared__ __align__(16) float sx [5][HHH][HWH]; // x-box-summed (cols 0..31; 36-pad)
    __shared__ float red[4];

    const int tid = threadIdx.x;
    const int bx = blockIdx.x, by = blockIdx.y;
    const int n  = blockIdx.z / NZC;
    const int c0 = (blockIdx.z % NZC) * ZCH;
    const int wbase = bx * TW - 2;
    const int hbase = by * TH - 2;
    const int nb = n * (D_ * HW_);

    // ---- Phase A ownership: 216 threads own 2 adjacent halo columns ----
    const bool aAct = tid < 216;
    const int arow = tid / 18;           // 0..11
    const int ag   = tid % 18;           // 0..17
    const int ah   = hbase + arow;
    const int aw0  = wbase + 2 * ag;     // even; aw0 in range implies aw0+1 too (W even)
    const bool aok = aAct && ((unsigned)ah < (unsigned)H_) && ((unsigned)aw0 < (unsigned)W_);
    const int aoff = ah * W_ + aw0;

    // per-column z-ring of raw I,J + incremental z-sums of the 5 quantities
    float rI0[5], rJ0[5], rI1[5], rJ1[5];
    float zs0[5], zs1[5];
#pragma unroll
    for (int k = 0; k < 5; ++k) { rI0[k]=0.f; rJ0[k]=0.f; rI1[k]=0.f; rJ1[k]=0.f; }
#pragma unroll
    for (int a = 0; a < 5; ++a) { zs0[a]=0.f; zs1[a]=0.f; }

    // ---- Phase B ownership: 96 threads, 4 x-outputs each ----
    const int brow = tid >> 3;           // 0..11 (for tid<96)
    const int bx0  = (tid & 7) * 4;

    // ---- Phase C ownership: 64 threads, 4 outputs each ----
    const int cty = tid >> 3;            // 0..7 (for tid<64)
    const int cx0 = (tid & 7) * 4;
    const int ch  = by * TH + cty;
    const int cw  = bx * TW + cx0;
    const int coff = ch * W_ + cw;

    // ---- pending (prefetched) global data ----
    float2 pI = make_float2(0.f, 0.f), pJ = make_float2(0.f, 0.f);
    {   // plane for A(0): z = c0-2
        const int z0 = c0 - 2;
        if (aok && z0 >= 0) {
            const int g = nb + z0 * HW_ + aoff;
            pI = *(const float2*)&I[g];
            pJ = *(const float2*)&J[g];
        }
    }
    float4 pWm = make_float4(0.f, 0.f, 0.f, 0.f);
    if (tid < 64) {   // Wm for first C output (zo = c0, consumed at t=5)
        pWm = *(const float4*)&Wm[nb + c0 * HW_ + coff];
    }

    float acc = 0.f;
    const float inv125 = 1.0f / 125.0f;

    // t=0..36: A handles plane z=c0-2+t (t<=35); B/C handle A's data of step t-1.
    for (int t = 0; t <= ZCH + 4; ++t) {

        // ---------- Phase B: x box-sum (36 -> 32) on zsL written at step t-1
        if (t >= 1 && tid < 96) {
#pragma unroll
            for (int a = 0; a < 5; ++a) {
                const float4 v0 = *(const float4*)&zsL[a][brow][bx0];
                const float4 v1 = *(const float4*)&zsL[a][brow][bx0 + 4];
                const float m  = v0.y + v0.z + v0.w;
                const float u1 = v1.x + v1.y;
                const float u2 = u1 + v1.z;
                const float o0 = v0.x + m + v1.x;
                const float o1 = m + u1;
                const float o2 = (v0.z + v0.w) + u2;
                const float o3 = v0.w + (u2 + v1.w);
                *(float4*)&sx[a][brow][bx0] = make_float4(o0, o1, o2, o3);
            }
        }
        __syncthreads();   // B done reading zsL (A may overwrite), sx visible to C

        // ---------- Phase A: consume prefetched plane, update z-sums, stage; issue next
        if (t <= ZCH + 3 && aAct) {
            const float iv0 = pI.x, iv1 = pI.y, jv0 = pJ.x, jv1 = pJ.y;

            // issue prefetch for plane consumed at t+1 (z = c0-1+t)
            float2 nI = make_float2(0.f, 0.f), nJ = make_float2(0.f, 0.f);
            const int zn = c0 - 1 + t;
            if (t <= ZCH + 2 && aok && (unsigned)zn < (unsigned)D_) {
                const int g = nb + zn * HW_ + aoff;
                nI = *(const float2*)&I[g];
                nJ = *(const float2*)&J[g];
            }
            pI = nI; pJ = nJ;

            {   // column 0: incremental z-window update
                const float oi = rI0[0], oj = rJ0[0];
                zs0[0] += iv0 - oi;
                zs0[1] += jv0 - oj;
                zs0[2] += iv0*iv0 - oi*oi;
                zs0[3] += jv0*jv0 - oj*oj;
                zs0[4] += iv0*jv0 - oi*oj;
#pragma unroll
                for (int k = 0; k < 4; ++k) { rI0[k]=rI0[k+1]; rJ0[k]=rJ0[k+1]; }
                rI0[4] = iv0; rJ0[4] = jv0;
            }
            {   // column 1
                const float oi = rI1[0], oj = rJ1[0];
                zs1[0] += iv1 - oi;
                zs1[1] += jv1 - oj;
                zs1[2] += iv1*iv1 - oi*oi;
                zs1[3] += jv1*jv1 - oj*oj;
                zs1[4] += iv1*jv1 - oi*oj;
#pragma unroll
                for (int k = 0; k < 4; ++k) { rI1[k]=rI1[k+1]; rJ1[k]=rJ1[k+1]; }
                rI1[4] = iv1; rJ1[4] = jv1;
            }
#pragma unroll
            for (int a = 0; a < 5; ++a)
                *(float2*)&zsL[a][arow][2*ag] = make_float2(zs0[a], zs1[a]);
        }

        // ---------- Phase C: y box-sum + cc on sx written by B this step
        if (t >= 5 && tid < 64) {
            const int zo = c0 - 5 + t;       // in [c0, c0+ZCH-1]
            float4 S[5];
#pragma unroll
            for (int a = 0; a < 5; ++a) {
                float4 v = *(const float4*)&sx[a][cty][cx0];
#pragma unroll
                for (int k = 1; k < 5; ++k) {
                    const float4 w = *(const float4*)&sx[a][cty + k][cx0];
                    v.x += w.x; v.y += w.y; v.z += w.z; v.w += w.w;
                }
                S[a] = v;
            }
            const float4 wm = pWm;
            // issue Wm prefetch for next step's output plane
            if (t <= ZCH + 3) {
                pWm = *(const float4*)&Wm[nb + (zo + 1) * HW_ + coff];
            }
            {
                const float cr = S[4].x - S[0].x * S[1].x * inv125;
                const float vi = S[2].x - S[0].x * S[0].x * inv125;
                const float vj = S[3].x - S[1].x * S[1].x * inv125;
                acc += wm.x * (cr * cr) * __builtin_amdgcn_rcpf(vi * vj + 1e-8f);
            }
            {
                const float cr = S[4].y - S[0].y * S[1].y * inv125;
                const float vi = S[2].y - S[0].y * S[0].y * inv125;
                const float vj = S[3].y - S[1].y * S[1].y * inv125;
                acc += wm.y * (cr * cr) * __builtin_amdgcn_rcpf(vi * vj + 1e-8f);
            }
            {
                const float cr = S[4].z - S[0].z * S[1].z * inv125;
                const float vi = S[2].z - S[0].z * S[0].z * inv125;
                const float vj = S[3].z - S[1].z * S[1].z * inv125;
                acc += wm.z * (cr * cr) * __builtin_amdgcn_rcpf(vi * vj + 1e-8f);
            }
            {
                const float cr = S[4].w - S[0].w * S[1].w * inv125;
                const float vi = S[2].w - S[0].w * S[0].w * inv125;
                const float vj = S[3].w - S[1].w * S[1].w * inv125;
                acc += wm.w * (cr * cr) * __builtin_amdgcn_rcpf(vi * vj + 1e-8f);
            }
        }

        __syncthreads();   // zsL(t) visible for B(t+1); C done with sx before B(t+1) rewrites
    }

    // Block reduction: wave64 shuffle, then cross-wave via LDS
#pragma unroll
    for (int off = 32; off > 0; off >>= 1)
        acc += __shfl_down(acc, off, 64);
    const int wave = tid >> 6;
    const int lane = tid & 63;
    if (lane == 0) red[wave] = acc;
    __syncthreads();
    if (tid == 0) {
        const float t = red[0] + red[1] + red[2] + red[3];
        atomicAdd(out, t * (-1.0f / (float)TOT));
    }
}

extern "C" void kernel_launch(void* const* d_in, const int* in_sizes, int n_in,
                              void* d_out, int out_size, void* d_ws, size_t ws_size,
                              hipStream_t stream)
{
    const float* I  = (const float*)d_in[0];
    const float* J  = (const float*)d_in[1];
    const float* Wm = (const float*)d_in[2];
    float* out = (float*)d_out;

    hipMemsetAsync(out, 0, sizeof(float), stream);

    dim3 grid(W_ / TW, H_ / TH, N_ * NZC);  // (7, 24, 10) = 1680 blocks
    dim3 block(256);
    hipLaunchKernelGGL(ncc_kernel, grid, block, 0, stream, I, J, Wm, out);
}